// Round 9
// baseline (356.313 us; speedup 1.0000x reference)
//
#include <hip/hip_runtime.h>
#include <hip/hip_bf16.h>

#define NUSERS 100000
#define NITEMS 50000
#define NN (NUSERS + NITEMS)      // 150000
#define NE 4000000
#define DIM 64
#define BQ 4096
#define NBIN ((NN + 255) >> 8)    // 586 bins of 256 rows
#define BINCAP 9216               // fixed slots/bin; mean w/ pads 7851, sigma ~90
#define EPB2 16384                // edges per block in pass A (64/thread)

typedef unsigned short u16;
typedef unsigned int u32;
typedef float v2f __attribute__((ext_vector_type(2)));

__device__ __forceinline__ float bf2f(u16 u) {
    return __uint_as_float(((unsigned)u) << 16);
}
__device__ __forceinline__ u16 f2bf(float f) {
    unsigned x = __float_as_uint(f);
    return (u16)((x + 0x7FFFu + ((x >> 16) & 1u)) >> 16);   // RNE
}
// unpack uint4 (8 bf16) into 4 packed-f32 accumulates (v_pk_add_f32)
__device__ __forceinline__ void add8p(v2f* acc2, uint4 u) {
    acc2[0] += (v2f){__uint_as_float(u.x << 16), __uint_as_float(u.x & 0xffff0000u)};
    acc2[1] += (v2f){__uint_as_float(u.y << 16), __uint_as_float(u.y & 0xffff0000u)};
    acc2[2] += (v2f){__uint_as_float(u.z << 16), __uint_as_float(u.z & 0xffff0000u)};
    acc2[3] += (v2f){__uint_as_float(u.w << 16), __uint_as_float(u.w & 0xffff0000u)};
}
// 32-bit voffset + SGPR base load: offset = c*128 + dgoff, fits 25 bits
__device__ __forceinline__ uint4 ld_row(const char* __restrict__ base, int c, int dgoff) {
    u32 off = ((u32)c << 7) + (u32)dgoff;
    return *(const uint4*)(base + off);
}

// Shared row-sum core: cols preloaded in c_all (lane l holds col_s[start+l]),
// all G<=8 gathers issued before any add (max MLP). G wave-uniform.
__device__ __forceinline__ void rowsum_core(int start, int n8, int c_all,
                                            const int* __restrict__ col_s,
                                            const char* __restrict__ inb,
                                            int eslot, int dgoff, v2f* acc2) {
    int G = n8 >> 3;
    if (G <= 8) {
        int cg[8];
#pragma unroll
        for (int g = 0; g < 8; ++g)
            cg[g] = __shfl(c_all, (g << 3) + eslot, 64);
        uint4 v[8];
#pragma unroll
        for (int g = 0; g < 8; ++g)
            if (g < G) v[g] = ld_row(inb, cg[g], dgoff);
#pragma unroll
        for (int g = 0; g < 8; ++g)
            if (g < G) add8p(acc2, v[g]);
    } else {
        // fallback (deg > 64): pipelined loop over col_s
        int i = eslot;
        int c0 = col_s[start + i];
        uint4 v0 = ld_row(inb, c0, dgoff);
        for (i += 8; i < n8; i += 8) {
            int c1 = col_s[start + i];
            uint4 v1 = ld_row(inb, c1, dgoff);
            add8p(acc2, v0);
            v0 = v1;
        }
        add8p(acc2, v0);
    }
}

// wave-wide reduction over the 8 edge slots (pairs stay packed)
__device__ __forceinline__ void reduce_acc(v2f* acc2) {
#pragma unroll
    for (int off = 8; off <= 32; off <<= 1)
#pragma unroll
        for (int j = 0; j < 4; ++j) {
            v2f o;
            o.x = __shfl_xor(acc2[j].x, off, 64);
            o.y = __shfl_xor(acc2[j].y, off, 64);
            acc2[j] += o;
        }
}

// ---------------- init: bin cursors, m2 mask, sentinel rows ----------------
__global__ void k_init(int* __restrict__ bin_cur, u32* __restrict__ m2w,
                       u16* __restrict__ ea, u16* __restrict__ eb) {
    int t = blockIdx.x * blockDim.x + threadIdx.x;
    if (t < NBIN) bin_cur[t] = t * BINCAP;
    if (t < 37504) m2w[t] = 0;                 // zero 150016 bytes of m2
    if (t < 32) {                              // zero sentinel row NN in both tables
        ((u32*)(ea + (size_t)NN * DIM))[t] = 0;
        ((u32*)(eb + (size_t)NN * DIM))[t] = 0;
    }
}

// ---------------- Pass A v2: block-local counting sort, coalesced flush -------
// Per block: histogram 16K edges by bin -> local scan -> reserve global chunk
// per bin -> scatter packed edges into LDS ordered by bin -> wave-cooperative
// flush (lanes write consecutive addresses; chunks ~112 B, dense lines).
// Packed u32: (row&255)<<24 | col  (col < 150000 < 2^24)
__global__ void k_binA2(const int* __restrict__ row, const int* __restrict__ col,
                        int* __restrict__ bin_cur, u32* __restrict__ pairs, int E) {
    __shared__ u32 stage[EPB2];            // 64 KB
    __shared__ int hist[NBIN];
    __shared__ int base_l[NBIN];
    __shared__ int cbase[NBIN];
    __shared__ int lcur[NBIN];
    __shared__ int tsum[256];
    int t = threadIdx.x;
    int base = blockIdx.x * EPB2;
    int lim = min(E - base, EPB2);

    for (int b = t; b < NBIN; b += 256) hist[b] = 0;
    __syncthreads();

    // P1: histogram by bin
    for (int i = t; i < lim; i += 256)
        atomicAdd(&hist[row[base + i] >> 8], 1);
    __syncthreads();

    // P2: exclusive scan of hist (thread t owns bins 3t..3t+2) + global reserve
    {
        int b0 = t * 3;
        int s0 = (b0 < NBIN) ? hist[b0] : 0;
        int s1 = (b0 + 1 < NBIN) ? hist[b0 + 1] : 0;
        int s2 = (b0 + 2 < NBIN) ? hist[b0 + 2] : 0;
        int tot = s0 + s1 + s2;
        tsum[t] = tot;
        __syncthreads();
        for (int off = 1; off < 256; off <<= 1) {
            int x = (t >= off) ? tsum[t - off] : 0;
            __syncthreads();
            tsum[t] += x;
            __syncthreads();
        }
        int excl = tsum[t] - tot;
        if (b0 < NBIN)     { base_l[b0] = excl;           lcur[b0] = excl; }
        if (b0 + 1 < NBIN) { base_l[b0 + 1] = excl + s0;  lcur[b0 + 1] = excl + s0; }
        if (b0 + 2 < NBIN) { base_l[b0 + 2] = excl + s0 + s1; lcur[b0 + 2] = excl + s0 + s1; }
    }
    for (int b = t; b < NBIN; b += 256) {
        int h = hist[b];
        cbase[b] = (h > 0) ? atomicAdd(&bin_cur[b], h) : 0;
    }
    __syncthreads();

    // P3: re-read edges (L2-hot), scatter into LDS stage ordered by bin
    for (int i = t; i < lim; i += 256) {
        int r = row[base + i];
        int c = col[base + i];
        int pos = atomicAdd(&lcur[r >> 8], 1);
        stage[pos] = ((u32)(r & 255) << 24) | (u32)c;
    }
    __syncthreads();

    // P4: wave-cooperative flush, one bin at a time per wave (coalesced stores)
    int wv = t >> 6;
    int lane = t & 63;
    for (int b = wv; b < NBIN; b += 4) {
        int h = hist[b];
        int lb = base_l[b];
        int gb = cbase[b];
        for (int i = lane; i < h; i += 64)
            pairs[(size_t)gb + i] = stage[lb + i];
    }
}

// ---------------- Pass B: per-bin row sort; derives rs/deg; pads to 8 ----------------
__global__ void k_binB(const u32* __restrict__ pairs, const int* __restrict__ bin_cur,
                       int* __restrict__ col_s, int* __restrict__ rs,
                       int* __restrict__ deg) {
    __shared__ int cnt[256];
    __shared__ int pscan[256];
    __shared__ int cur[256];
    int b = blockIdx.x;
    int t = threadIdx.x;
    int base = b * BINCAP;
    int end = bin_cur[b];
    cnt[t] = 0;
    __syncthreads();
    for (int i = base + t; i < end; i += 256)
        atomicAdd(&cnt[pairs[i] >> 24], 1);
    __syncthreads();
    int v = cnt[t];
    int pv = (v + 7) & ~7;                    // row segment padded to multiple of 8
    pscan[t] = pv;
    __syncthreads();
    for (int off = 1; off < 256; off <<= 1) {
        int x = (t >= off) ? pscan[t - off] : 0;
        __syncthreads();
        pscan[t] += x;
        __syncthreads();
    }
    int rowstart = base + pscan[t] - pv;
    int r = (b << 8) + t;
    if (r < NN) {
        rs[r] = rowstart;
        deg[r] = v;
    }
    cur[t] = rowstart;
    for (int i = v; i < pv; ++i) col_s[rowstart + i] = NN;   // sentinel pads
    __syncthreads();
    for (int i = base + t; i < end; i += 256) {
        u32 p = pairs[i];
        int pos = atomicAdd(&cur[p >> 24], 1);
        col_s[pos] = (int)(p & 0x00FFFFFFu);
    }
}

// ---------------- t0 = dis ⊙ emb0, bf16 ----------------
__global__ void k_concat_t0(const float* __restrict__ u, const float* __restrict__ it,
                            const int* __restrict__ deg, u16* __restrict__ emb) {
    int i = blockIdx.x * blockDim.x + threadIdx.x;   // ushort4 index (4 dims), 16/row
    const int NU4 = NUSERS * DIM / 4;
    const int NT4 = NN * DIM / 4;
    if (i >= NT4) return;
    int row = i >> 4;
    int d = deg[row];
    float sc = (d > 0) ? (1.0f / sqrtf((float)d)) : 0.0f;
    float4 v = (i < NU4) ? ((const float4*)u)[i] : ((const float4*)it)[i - NU4];
    ushort4 o;
    o.x = f2bf(sc * v.x); o.y = f2bf(sc * v.y);
    o.z = f2bf(sc * v.z); o.w = f2bf(sc * v.w);
    ((ushort4*)emb)[i] = o;
}

// mark rows needed for hop-2 output: one wave per query row, lanes scatter
__global__ void k_mark(const int* __restrict__ uid, const int* __restrict__ iid,
                       const int* __restrict__ rs, const int* __restrict__ deg,
                       const int* __restrict__ col_s, unsigned char* __restrict__ m2) {
    int q = (blockIdx.x * blockDim.x + threadIdx.x) >> 6;
    if (q >= 2 * BQ) return;
    int lane = threadIdx.x & 63;
    int r = (q < BQ) ? uid[q] : (NUSERS + iid[q - BQ]);
    if (lane == 0) m2[r] = 1;
    int s = rs[r], n = deg[r];
    for (int i = lane; i < n; i += 64) m2[col_s[s + i]] = 1;
}

// ---------------- SpMM in t-space: one wave per row ----------------
// t_{k+1}[r] = (1/deg[r]) * sum_{c in N(r)} t_k[c]
__global__ void k_spmm8(const int* __restrict__ rs, const int* __restrict__ deg,
                        const int* __restrict__ col_s, const u16* __restrict__ in,
                        u16* __restrict__ out, const unsigned char* __restrict__ mask) {
    int wid = (blockIdx.x * blockDim.x + threadIdx.x) >> 6;
    if (wid >= NN) return;
    if (mask && !mask[wid]) return;
    int lane = threadIdx.x & 63;
    int eslot = lane >> 3;
    int dg = lane & 7;
    int dgoff = dg << 4;
    int n = deg[wid];
    int start = rs[wid];
    int n8 = (n + 7) & ~7;
    int c_all = col_s[start + lane];           // preload up to 64 cols
    const char* inb = (const char*)in;
    v2f acc2[4] = {(v2f)0.f, (v2f)0.f, (v2f)0.f, (v2f)0.f};
    if (n8 > 0)
        rowsum_core(start, n8, c_all, col_s, inb, eslot, dgoff, acc2);
    reduce_acc(acc2);
    if (eslot == 0) {
        float s = (n > 0) ? (1.0f / (float)n) : 0.0f;  // dis[r]^2
        v2f vs = {s, s};
        u32 p[4];
#pragma unroll
        for (int j = 0; j < 4; ++j) {
            v2f r = acc2[j] * vs;
            __hip_bfloat162 h = __float22bfloat162_rn(make_float2(r.x, r.y));
            p[j] = *(u32*)&h;
        }
        ((uint4*)out)[(size_t)wid * 8 + dg] = make_uint4(p[0], p[1], p[2], p[3]);
    }
}

// hop-3 fused: one wave per query slot; out = (out + dis[r]*sum t2[c]) * 0.25
__global__ void k_spmm_out(const int* __restrict__ rs, const int* __restrict__ deg,
                           const int* __restrict__ col_s, const u16* __restrict__ in,
                           const int* __restrict__ uid, const int* __restrict__ iid,
                           float* __restrict__ out) {
    int q = (blockIdx.x * blockDim.x + threadIdx.x) >> 6;
    if (q >= 2 * BQ) return;
    int lane = threadIdx.x & 63;
    int eslot = lane >> 3;
    int dg = lane & 7;
    int dgoff = dg << 4;
    int b, r, off;
    if (q < BQ) { b = q; r = uid[q]; off = 0; }
    else { b = q - BQ; r = NUSERS + iid[q - BQ]; off = DIM; }
    int n = deg[r];
    int start = rs[r];
    int n8 = (n + 7) & ~7;
    int c_all = col_s[start + lane];
    const char* inb = (const char*)in;
    v2f acc2[4] = {(v2f)0.f, (v2f)0.f, (v2f)0.f, (v2f)0.f};
    if (n8 > 0)
        rowsum_core(start, n8, c_all, col_s, inb, eslot, dgoff, acc2);
    reduce_acc(acc2);
    if (eslot == 0) {
        float dr = (n > 0) ? (1.0f / sqrtf((float)n)) : 0.0f;   // dis[r]
        float* o = out + (size_t)b * (2 * DIM) + off + dg * 8;
#pragma unroll
        for (int j = 0; j < 4; ++j) {
            o[2 * j]     = (o[2 * j]     + dr * acc2[j].x) * 0.25f;
            o[2 * j + 1] = (o[2 * j + 1] + dr * acc2[j].y) * 0.25f;
        }
    }
}

// ---------------- output gathers ----------------

__global__ void k_gather_init(const int* __restrict__ uid, const int* __restrict__ iid,
                              const float* __restrict__ u, const float* __restrict__ it,
                              float* __restrict__ out) {
    int t = blockIdx.x * blockDim.x + threadIdx.x;
    if (t >= BQ * DIM) return;
    int b = t >> 6;
    int d = t & 63;
    out[b * (2 * DIM) + d]       = u[(size_t)uid[b] * DIM + d];
    out[b * (2 * DIM) + DIM + d] = it[(size_t)iid[b] * DIM + d];
}

// out += sqrt(deg[r]) * t_k[r]   (emb_k = rdis ⊙ t_k)
__global__ void k_gather_add(const int* __restrict__ uid, const int* __restrict__ iid,
                             const int* __restrict__ deg, const u16* __restrict__ emb,
                             float* __restrict__ out) {
    int t = blockIdx.x * blockDim.x + threadIdx.x;
    if (t >= BQ * DIM) return;
    int b = t >> 6;
    int d = t & 63;
    int ru = uid[b];
    int ri = NUSERS + iid[b];
    int du = deg[ru], di = deg[ri];
    float su = (du > 0) ? sqrtf((float)du) : 0.0f;
    float si = (di > 0) ? sqrtf((float)di) : 0.0f;
    int ou = b * (2 * DIM) + d;
    int oi = ou + DIM;
    out[ou] = out[ou] + su * bf2f(emb[(size_t)ru * DIM + d]);
    out[oi] = out[oi] + si * bf2f(emb[(size_t)ri * DIM + d]);
}

// ---------------- launch ----------------

extern "C" void kernel_launch(void* const* d_in, const int* in_sizes, int n_in,
                              void* d_out, int out_size, void* d_ws, size_t ws_size,
                              hipStream_t stream) {
    const float* users_emb = (const float*)d_in[0];
    const float* items_emb = (const float*)d_in[1];
    const int*   edge_row  = (const int*)d_in[2];
    const int*   edge_col  = (const int*)d_in[3];
    const int*   user_id   = (const int*)d_in[4];
    const int*   item_ids  = (const int*)d_in[5];
    float* out = (float*)d_out;

    char* ws = (char*)d_ws;
    // byte layout (ends ~90.3 MB):
    int*   deg_i   = (int*)  (ws + 0);          // 600 KB
    int*   rs      = (int*)  (ws + 655360);     // 600 KB
    int*   bin_cur = (int*)  (ws + 1310720);    // 2.4 KB
    unsigned char* m2 = (unsigned char*)(ws + 1400000);  // 150 KB
    int*   col_s   = (int*)  (ws + 4194304);    // 586*9216*4 = 21.6 MB
    u32*   pairs   = (u32*)  (ws + 29360128);   // 21.6 MB
    u16*   emb_a   = (u16*)  (ws + 54525952);   // (NN+1)*64*2 = 19.2 MB
    u16*   emb_b   = (u16*)  (ws + 75497472);   // 19.2 MB

    // init cursors + m2 + sentinel rows
    k_init<<<147, 256, 0, stream>>>(bin_cur, (u32*)m2, emb_a, emb_b);

    // binned CSR build (counting-sort pass A; pass B derives deg/rs, pads to x8)
    k_binA2<<<(NE + EPB2 - 1) / EPB2, 256, 0, stream>>>(edge_row, edge_col, bin_cur,
                                                        pairs, NE);
    k_binB<<<NBIN, 256, 0, stream>>>(pairs, bin_cur, col_s, rs, deg_i);

    // t0 table (bf16, dis-folded)
    k_concat_t0<<<(NN * DIM / 4 + 255) / 256, 256, 0, stream>>>(users_emb, items_emb,
                                                                deg_i, emb_a);

    // layer-0 contribution (fp32 sources)
    k_gather_init<<<(BQ * DIM + 255) / 256, 256, 0, stream>>>(user_id, item_ids,
                                                              users_emb, items_emb, out);

    // mark rows whose hop-2 output is read (one wave per query row)
    k_mark<<<(2 * BQ + 3) / 4, 256, 0, stream>>>(user_id, item_ids, rs, deg_i, col_s, m2);

    const int spmm_blocks = (NN + 3) / 4;
    // hop 1: full
    k_spmm8<<<spmm_blocks, 256, 0, stream>>>(rs, deg_i, col_s, emb_a, emb_b,
                                             (const unsigned char*)nullptr);
    k_gather_add<<<(BQ * DIM + 255) / 256, 256, 0, stream>>>(user_id, item_ids, deg_i,
                                                             emb_b, out);
    // hop 2: masked
    k_spmm8<<<spmm_blocks, 256, 0, stream>>>(rs, deg_i, col_s, emb_b, emb_a, m2);
    k_gather_add<<<(BQ * DIM + 255) / 256, 256, 0, stream>>>(user_id, item_ids, deg_i,
                                                             emb_a, out);
    // hop 3: fused into output, fp32 accumulate, final /4
    k_spmm_out<<<(2 * BQ + 3) / 4, 256, 0, stream>>>(rs, deg_i, col_s, emb_a,
                                                     user_id, item_ids, out);
}

// Round 10
// 307.124 us; speedup vs baseline: 1.1602x; 1.1602x over previous
//
#include <hip/hip_runtime.h>
#include <hip/hip_bf16.h>

#define NUSERS 100000
#define NITEMS 50000
#define NN (NUSERS + NITEMS)      // 150000
#define NE 4000000
#define DIM 64
#define BQ 4096
#define NBIN ((NN + 255) >> 8)    // 586 bins of 256 rows
#define BINCAP 9216               // fixed slots/bin; mean w/ pads 7851, sigma ~90
#define EPB2 8192                 // edges per block in pass A (8/thread @ 1024)

typedef unsigned short u16;
typedef unsigned int u32;
typedef float v2f __attribute__((ext_vector_type(2)));

__device__ __forceinline__ float bf2f(u16 u) {
    return __uint_as_float(((unsigned)u) << 16);
}
__device__ __forceinline__ u16 f2bf(float f) {
    unsigned x = __float_as_uint(f);
    return (u16)((x + 0x7FFFu + ((x >> 16) & 1u)) >> 16);   // RNE
}
// unpack uint4 (8 bf16) into 4 packed-f32 accumulates (v_pk_add_f32)
__device__ __forceinline__ void add8p(v2f* acc2, uint4 u) {
    acc2[0] += (v2f){__uint_as_float(u.x << 16), __uint_as_float(u.x & 0xffff0000u)};
    acc2[1] += (v2f){__uint_as_float(u.y << 16), __uint_as_float(u.y & 0xffff0000u)};
    acc2[2] += (v2f){__uint_as_float(u.z << 16), __uint_as_float(u.z & 0xffff0000u)};
    acc2[3] += (v2f){__uint_as_float(u.w << 16), __uint_as_float(u.w & 0xffff0000u)};
}
// 32-bit voffset + SGPR base load: offset = c*128 + dgoff, fits 25 bits
__device__ __forceinline__ uint4 ld_row(const char* __restrict__ base, int c, int dgoff) {
    u32 off = ((u32)c << 7) + (u32)dgoff;
    return *(const uint4*)(base + off);
}

// Shared row-sum core: cols preloaded in c_all (lane l holds col_s[start+l]),
// all G<=8 gathers issued before any add (max MLP). G wave-uniform.
__device__ __forceinline__ void rowsum_core(int start, int n8, int c_all,
                                            const int* __restrict__ col_s,
                                            const char* __restrict__ inb,
                                            int eslot, int dgoff, v2f* acc2) {
    int G = n8 >> 3;
    if (G <= 8) {
        int cg[8];
#pragma unroll
        for (int g = 0; g < 8; ++g)
            cg[g] = __shfl(c_all, (g << 3) + eslot, 64);
        uint4 v[8];
#pragma unroll
        for (int g = 0; g < 8; ++g)
            if (g < G) v[g] = ld_row(inb, cg[g], dgoff);
#pragma unroll
        for (int g = 0; g < 8; ++g)
            if (g < G) add8p(acc2, v[g]);
    } else {
        // fallback (deg > 64): pipelined loop over col_s
        int i = eslot;
        int c0 = col_s[start + i];
        uint4 v0 = ld_row(inb, c0, dgoff);
        for (i += 8; i < n8; i += 8) {
            int c1 = col_s[start + i];
            uint4 v1 = ld_row(inb, c1, dgoff);
            add8p(acc2, v0);
            v0 = v1;
        }
        add8p(acc2, v0);
    }
}

// wave-wide reduction over the 8 edge slots (pairs stay packed)
__device__ __forceinline__ void reduce_acc(v2f* acc2) {
#pragma unroll
    for (int off = 8; off <= 32; off <<= 1)
#pragma unroll
        for (int j = 0; j < 4; ++j) {
            v2f o;
            o.x = __shfl_xor(acc2[j].x, off, 64);
            o.y = __shfl_xor(acc2[j].y, off, 64);
            acc2[j] += o;
        }
}

// ---------------- init: bin cursors, m2 mask, sentinel rows ----------------
__global__ void k_init(int* __restrict__ bin_cur, u32* __restrict__ m2w,
                       u16* __restrict__ ea, u16* __restrict__ eb) {
    int t = blockIdx.x * blockDim.x + threadIdx.x;
    if (t < NBIN) bin_cur[t] = t * BINCAP;
    if (t < 37504) m2w[t] = 0;                 // zero 150016 bytes of m2
    if (t < 32) {                              // zero sentinel row NN in both tables
        ((u32*)(ea + (size_t)NN * DIM))[t] = 0;
        ((u32*)(eb + (size_t)NN * DIM))[t] = 0;
    }
}

// ---------------- Pass A: block-local counting sort, coalesced flush -------
// 1024 threads, 8K edges/block: histogram by bin -> 1024-wide scan -> reserve
// global chunk per bin -> scatter packed edges into LDS ordered by bin ->
// wave-cooperative flush (consecutive addresses, dense lines).
// Packed u32: (row&255)<<24 | col  (col < 150000 < 2^24)
__global__ void __launch_bounds__(1024) k_binA2(
        const int* __restrict__ row, const int* __restrict__ col,
        int* __restrict__ bin_cur, u32* __restrict__ pairs, int E) {
    __shared__ u32 stage[EPB2];            // 32 KB
    __shared__ int hist[NBIN];
    __shared__ int base_l[NBIN];
    __shared__ int cbase[NBIN];
    __shared__ int lcur[NBIN];
    __shared__ int s[1024];
    int t = threadIdx.x;
    int base = blockIdx.x * EPB2;
    int lim = min(E - base, EPB2);

    if (t < NBIN) hist[t] = 0;
    __syncthreads();

    // P1: histogram by bin
    for (int i = t; i < lim; i += 1024)
        atomicAdd(&hist[row[base + i] >> 8], 1);
    __syncthreads();

    // P2: 1024-wide exclusive scan of hist + per-bin global chunk reserve
    int v = (t < NBIN) ? hist[t] : 0;
    s[t] = v;
    __syncthreads();
    for (int off = 1; off < 1024; off <<= 1) {
        int x = (t >= off) ? s[t - off] : 0;
        __syncthreads();
        s[t] += x;
        __syncthreads();
    }
    if (t < NBIN) {
        int excl = s[t] - v;
        base_l[t] = excl;
        lcur[t] = excl;
        cbase[t] = (v > 0) ? atomicAdd(&bin_cur[t], v) : 0;
    }
    __syncthreads();

    // P3: re-read edges (L2-hot), scatter into LDS stage ordered by bin
    for (int i = t; i < lim; i += 1024) {
        int r = row[base + i];
        int c = col[base + i];
        int pos = atomicAdd(&lcur[r >> 8], 1);
        stage[pos] = ((u32)(r & 255) << 24) | (u32)c;
    }
    __syncthreads();

    // P4: wave-cooperative flush, one bin per wave (coalesced stores)
    int wv = t >> 6;
    int lane = t & 63;
    for (int b = wv; b < NBIN; b += 16) {
        int h = hist[b];
        int lb = base_l[b];
        size_t gb = (size_t)cbase[b];
        for (int i = lane; i < h; i += 64)
            pairs[gb + i] = stage[lb + i];
    }
}

// ---------------- Pass B: per-bin row sort; derives rs/deg; pads to 8 ----------------
__global__ void __launch_bounds__(1024) k_binB(
        const u32* __restrict__ pairs, const int* __restrict__ bin_cur,
        int* __restrict__ col_s, int* __restrict__ rs, int* __restrict__ deg) {
    __shared__ int cnt[256];
    __shared__ int pscan[256];
    __shared__ int cur[256];
    int b = blockIdx.x;
    int t = threadIdx.x;
    int base = b * BINCAP;
    int end = bin_cur[b];
    if (t < 256) cnt[t] = 0;
    __syncthreads();
    for (int i = base + t; i < end; i += 1024)
        atomicAdd(&cnt[pairs[i] >> 24], 1);
    __syncthreads();
    int v = (t < 256) ? cnt[t] : 0;
    int pv = (v + 7) & ~7;                    // row segment padded to multiple of 8
    if (t < 256) pscan[t] = pv;
    __syncthreads();
    for (int off = 1; off < 256; off <<= 1) {
        int x = (t >= off && t < 256) ? pscan[t - off] : 0;
        __syncthreads();
        if (t < 256) pscan[t] += x;
        __syncthreads();
    }
    if (t < 256) {
        int rowstart = base + pscan[t] - pv;
        int r = (b << 8) + t;
        if (r < NN) {
            rs[r] = rowstart;
            deg[r] = v;
        }
        cur[t] = rowstart;
        for (int i = v; i < pv; ++i) col_s[rowstart + i] = NN;   // sentinel pads
    }
    __syncthreads();
    for (int i = base + t; i < end; i += 1024) {
        u32 p = pairs[i];
        int pos = atomicAdd(&cur[p >> 24], 1);
        col_s[pos] = (int)(p & 0x00FFFFFFu);
    }
}

// ---------------- t0 = dis ⊙ emb0, bf16 ----------------
__global__ void k_concat_t0(const float* __restrict__ u, const float* __restrict__ it,
                            const int* __restrict__ deg, u16* __restrict__ emb) {
    int i = blockIdx.x * blockDim.x + threadIdx.x;   // ushort4 index (4 dims), 16/row
    const int NU4 = NUSERS * DIM / 4;
    const int NT4 = NN * DIM / 4;
    if (i >= NT4) return;
    int row = i >> 4;
    int d = deg[row];
    float sc = (d > 0) ? (1.0f / sqrtf((float)d)) : 0.0f;
    float4 v = (i < NU4) ? ((const float4*)u)[i] : ((const float4*)it)[i - NU4];
    ushort4 o;
    o.x = f2bf(sc * v.x); o.y = f2bf(sc * v.y);
    o.z = f2bf(sc * v.z); o.w = f2bf(sc * v.w);
    ((ushort4*)emb)[i] = o;
}

// mark rows needed for hop-2 output: one wave per query row, lanes scatter
__global__ void k_mark(const int* __restrict__ uid, const int* __restrict__ iid,
                       const int* __restrict__ rs, const int* __restrict__ deg,
                       const int* __restrict__ col_s, unsigned char* __restrict__ m2) {
    int q = (blockIdx.x * blockDim.x + threadIdx.x) >> 6;
    if (q >= 2 * BQ) return;
    int lane = threadIdx.x & 63;
    int r = (q < BQ) ? uid[q] : (NUSERS + iid[q - BQ]);
    if (lane == 0) m2[r] = 1;
    int s = rs[r], n = deg[r];
    for (int i = lane; i < n; i += 64) m2[col_s[s + i]] = 1;
}

// ---------------- SpMM in t-space: one wave per row ----------------
// t_{k+1}[r] = (1/deg[r]) * sum_{c in N(r)} t_k[c]
__global__ void k_spmm8(const int* __restrict__ rs, const int* __restrict__ deg,
                        const int* __restrict__ col_s, const u16* __restrict__ in,
                        u16* __restrict__ out, const unsigned char* __restrict__ mask) {
    int wid = (blockIdx.x * blockDim.x + threadIdx.x) >> 6;
    if (wid >= NN) return;
    if (mask && !mask[wid]) return;
    int lane = threadIdx.x & 63;
    int eslot = lane >> 3;
    int dg = lane & 7;
    int dgoff = dg << 4;
    int n = deg[wid];
    int start = rs[wid];
    int n8 = (n + 7) & ~7;
    int c_all = col_s[start + lane];           // preload up to 64 cols
    const char* inb = (const char*)in;
    v2f acc2[4] = {(v2f)0.f, (v2f)0.f, (v2f)0.f, (v2f)0.f};
    if (n8 > 0)
        rowsum_core(start, n8, c_all, col_s, inb, eslot, dgoff, acc2);
    reduce_acc(acc2);
    if (eslot == 0) {
        float s = (n > 0) ? (1.0f / (float)n) : 0.0f;  // dis[r]^2
        v2f vs = {s, s};
        u32 p[4];
#pragma unroll
        for (int j = 0; j < 4; ++j) {
            v2f r = acc2[j] * vs;
            __hip_bfloat162 h = __float22bfloat162_rn(make_float2(r.x, r.y));
            p[j] = *(u32*)&h;
        }
        ((uint4*)out)[(size_t)wid * 8 + dg] = make_uint4(p[0], p[1], p[2], p[3]);
    }
}

// hop-3 fused: one wave per query slot; out = (out + dis[r]*sum t2[c]) * 0.25
__global__ void k_spmm_out(const int* __restrict__ rs, const int* __restrict__ deg,
                           const int* __restrict__ col_s, const u16* __restrict__ in,
                           const int* __restrict__ uid, const int* __restrict__ iid,
                           float* __restrict__ out) {
    int q = (blockIdx.x * blockDim.x + threadIdx.x) >> 6;
    if (q >= 2 * BQ) return;
    int lane = threadIdx.x & 63;
    int eslot = lane >> 3;
    int dg = lane & 7;
    int dgoff = dg << 4;
    int b, r, off;
    if (q < BQ) { b = q; r = uid[q]; off = 0; }
    else { b = q - BQ; r = NUSERS + iid[q - BQ]; off = DIM; }
    int n = deg[r];
    int start = rs[r];
    int n8 = (n + 7) & ~7;
    int c_all = col_s[start + lane];
    const char* inb = (const char*)in;
    v2f acc2[4] = {(v2f)0.f, (v2f)0.f, (v2f)0.f, (v2f)0.f};
    if (n8 > 0)
        rowsum_core(start, n8, c_all, col_s, inb, eslot, dgoff, acc2);
    reduce_acc(acc2);
    if (eslot == 0) {
        float dr = (n > 0) ? (1.0f / sqrtf((float)n)) : 0.0f;   // dis[r]
        float* o = out + (size_t)b * (2 * DIM) + off + dg * 8;
#pragma unroll
        for (int j = 0; j < 4; ++j) {
            o[2 * j]     = (o[2 * j]     + dr * acc2[j].x) * 0.25f;
            o[2 * j + 1] = (o[2 * j + 1] + dr * acc2[j].y) * 0.25f;
        }
    }
}

// ---------------- output gathers ----------------

__global__ void k_gather_init(const int* __restrict__ uid, const int* __restrict__ iid,
                              const float* __restrict__ u, const float* __restrict__ it,
                              float* __restrict__ out) {
    int t = blockIdx.x * blockDim.x + threadIdx.x;
    if (t >= BQ * DIM) return;
    int b = t >> 6;
    int d = t & 63;
    out[b * (2 * DIM) + d]       = u[(size_t)uid[b] * DIM + d];
    out[b * (2 * DIM) + DIM + d] = it[(size_t)iid[b] * DIM + d];
}

// out += sqrt(deg[r]) * t_k[r]   (emb_k = rdis ⊙ t_k)
__global__ void k_gather_add(const int* __restrict__ uid, const int* __restrict__ iid,
                             const int* __restrict__ deg, const u16* __restrict__ emb,
                             float* __restrict__ out) {
    int t = blockIdx.x * blockDim.x + threadIdx.x;
    if (t >= BQ * DIM) return;
    int b = t >> 6;
    int d = t & 63;
    int ru = uid[b];
    int ri = NUSERS + iid[b];
    int du = deg[ru], di = deg[ri];
    float su = (du > 0) ? sqrtf((float)du) : 0.0f;
    float si = (di > 0) ? sqrtf((float)di) : 0.0f;
    int ou = b * (2 * DIM) + d;
    int oi = ou + DIM;
    out[ou] = out[ou] + su * bf2f(emb[(size_t)ru * DIM + d]);
    out[oi] = out[oi] + si * bf2f(emb[(size_t)ri * DIM + d]);
}

// ---------------- launch ----------------

extern "C" void kernel_launch(void* const* d_in, const int* in_sizes, int n_in,
                              void* d_out, int out_size, void* d_ws, size_t ws_size,
                              hipStream_t stream) {
    const float* users_emb = (const float*)d_in[0];
    const float* items_emb = (const float*)d_in[1];
    const int*   edge_row  = (const int*)d_in[2];
    const int*   edge_col  = (const int*)d_in[3];
    const int*   user_id   = (const int*)d_in[4];
    const int*   item_ids  = (const int*)d_in[5];
    float* out = (float*)d_out;

    char* ws = (char*)d_ws;
    // byte layout (ends ~90.3 MB):
    int*   deg_i   = (int*)  (ws + 0);          // 600 KB
    int*   rs      = (int*)  (ws + 655360);     // 600 KB
    int*   bin_cur = (int*)  (ws + 1310720);    // 2.4 KB
    unsigned char* m2 = (unsigned char*)(ws + 1400000);  // 150 KB
    int*   col_s   = (int*)  (ws + 4194304);    // 586*9216*4 = 21.6 MB
    u32*   pairs   = (u32*)  (ws + 29360128);   // 21.6 MB
    u16*   emb_a   = (u16*)  (ws + 54525952);   // (NN+1)*64*2 = 19.2 MB
    u16*   emb_b   = (u16*)  (ws + 75497472);   // 19.2 MB

    // init cursors + m2 + sentinel rows
    k_init<<<147, 256, 0, stream>>>(bin_cur, (u32*)m2, emb_a, emb_b);

    // binned CSR build (counting-sort pass A; pass B derives deg/rs, pads to x8)
    k_binA2<<<(NE + EPB2 - 1) / EPB2, 1024, 0, stream>>>(edge_row, edge_col, bin_cur,
                                                         pairs, NE);
    k_binB<<<NBIN, 1024, 0, stream>>>(pairs, bin_cur, col_s, rs, deg_i);

    // t0 table (bf16, dis-folded)
    k_concat_t0<<<(NN * DIM / 4 + 255) / 256, 256, 0, stream>>>(users_emb, items_emb,
                                                                deg_i, emb_a);

    // layer-0 contribution (fp32 sources)
    k_gather_init<<<(BQ * DIM + 255) / 256, 256, 0, stream>>>(user_id, item_ids,
                                                              users_emb, items_emb, out);

    // mark rows whose hop-2 output is read (one wave per query row)
    k_mark<<<(2 * BQ + 3) / 4, 256, 0, stream>>>(user_id, item_ids, rs, deg_i, col_s, m2);

    const int spmm_blocks = (NN + 3) / 4;
    // hop 1: full
    k_spmm8<<<spmm_blocks, 256, 0, stream>>>(rs, deg_i, col_s, emb_a, emb_b,
                                             (const unsigned char*)nullptr);
    k_gather_add<<<(BQ * DIM + 255) / 256, 256, 0, stream>>>(user_id, item_ids, deg_i,
                                                             emb_b, out);
    // hop 2: masked
    k_spmm8<<<spmm_blocks, 256, 0, stream>>>(rs, deg_i, col_s, emb_b, emb_a, m2);
    k_gather_add<<<(BQ * DIM + 255) / 256, 256, 0, stream>>>(user_id, item_ids, deg_i,
                                                             emb_a, out);
    // hop 3: fused into output, fp32 accumulate, final /4
    k_spmm_out<<<(2 * BQ + 3) / 4, 256, 0, stream>>>(rs, deg_i, col_s, emb_a,
                                                     user_id, item_ids, out);
}